// Round 5
// baseline (82.582 us; speedup 1.0000x reference)
//
#include <hip/hip_runtime.h>
#include <hip/hip_bf16.h>

typedef __attribute__((ext_vector_type(8))) short bf16x8;
typedef __attribute__((ext_vector_type(4))) float f32x4;

#define GRU_B 131072
#define BM 32

static __device__ __forceinline__ ushort f2bf(float f) {
  union { float f; unsigned u; } v; v.f = f;
  unsigned r = v.u + 0x7FFFu + ((v.u >> 16) & 1u);   // RNE
  return (ushort)(r >> 16);
}
static __device__ __forceinline__ float bf2f(ushort u) {
  union { unsigned u; float f; } v; v.u = ((unsigned)u) << 16;
  return v.f;
}
static __device__ __forceinline__ unsigned pk2(float a, float b) {
  float2 t; t.x = a; t.y = b;
  __hip_bfloat162 r = __float22bfloat162_rn(t);      // v_cvt_pk_bf16_f32
  union { __hip_bfloat162 b; unsigned u; } cv; cv.b = r;
  return cv.u;
}
static __device__ __forceinline__ float fsig(float x) {
  return __builtin_amdgcn_rcpf(1.0f + __expf(-x));
}
static __device__ __forceinline__ float ftanh(float x) {
  return 1.0f - 2.0f * __builtin_amdgcn_rcpf(1.0f + __expf(2.0f * x));
}
static __device__ __forceinline__ f32x4 splat4(float s) {
  f32x4 v = {s, s, s, s}; return v;
}

// Pack six 128x128 fp32 weight matrices into per-lane MFMA B-fragment order:
// chunk = ((mat*8 + cb)*4 + kb), 1KB each; within chunk lane*16B holds
// w[kb*32 + (lane>>4)*8 + e][cb*16 + (lane&15)], e=0..7, bf16.
// A B-frag load is ONE coalesced global_load_dwordx4 at chunk + lane*16.
__global__ void wtrans_kernel(const float* __restrict__ wz, const float* __restrict__ uz,
                              const float* __restrict__ wr, const float* __restrict__ ur,
                              const float* __restrict__ wh, const float* __restrict__ uh,
                              ushort* __restrict__ outw) {
  int f = blockIdx.x * 256 + threadIdx.x;          // 0..98303 (coalesced write)
  int mat = f >> 14;
  int rem = f & 16383;
  int chunk = rem >> 9;                            // 0..31
  int lane = (rem >> 3) & 63;
  int e = rem & 7;
  int cb = chunk >> 2, k0b = chunk & 3;
  int n = cb * 16 + (lane & 15);
  int k = k0b * 32 + (lane >> 4) * 8 + e;
  const float* src = (mat == 0) ? wz : (mat == 1) ? uz : (mat == 2) ? wr
                   : (mat == 3) ? ur : (mat == 4) ? wh : uh;
  outw[f] = f2bf(src[k * 128 + n]);
}

#define MFMA __builtin_amdgcn_mfma_f32_16x16x32_bf16

__global__ __launch_bounds__(512, 8) void gru_kernel(
    const float* __restrict__ x, const float* __restrict__ hprev,
    const ushort* __restrict__ wt,
    const float* __restrict__ bz, const float* __restrict__ br,
    const float* __restrict__ bh, float* __restrict__ out) {
  // 16 KB total: xs[0..8K) hs[8K..16K); rh overwrites xs; f32 out-tile = all 16K
  __shared__ __align__(16) char smem[16384];
  ushort* xs = (ushort*)smem;
  ushort* hs = (ushort*)(smem + 8192);

  const int tid = threadIdx.x;
  const int lane = tid & 63;
  const int wid = tid >> 6;          // 8 waves: 16 output cols each
  const int l15 = lane & 15;
  const int q = lane >> 4;
  const long row0 = (long)blockIdx.x * BM;
  const int n0 = wid * 16;

  // per-lane biases (folded into accumulator init)
  float brv = br[n0 + l15];
  float bzv = bz[n0 + l15];
  float bhv = bh[n0 + l15];

  const ushort* wlane = wt + (lane << 3);
  auto wfrag = [&](int mat, int kb) -> const bf16x8* {
    // chunk index = (mat*8 + wid)*4 + kb, 512 ushorts each
    return (const bf16x8*)(wlane + ((((mat << 3) + wid) << 2) + kb) * 512);
  };

  // ---------------- stage x, h -> LDS bf16 (swizzled rows, 256 B/row) -------
  {
    const float4* xg = (const float4*)(x + row0 * 128);
    const float4* hg = (const float4*)(hprev + row0 * 128);
#pragma unroll
    for (int i = 0; i < 2; ++i) {
      int idx = i * 512 + tid;        // float4 index, 0..1023
      int r = idx >> 5;               // row 0..31
      int cbyte = (idx & 31) << 3;    // byte-in-row (col*2)
      int bo = (r * 256 + cbyte) ^ ((r & 7) << 4);
      float4 xv = xg[idx];
      float4 hv = hg[idx];
      uint2 xp, hp;
      xp.x = pk2(xv.x, xv.y); xp.y = pk2(xv.z, xv.w);
      hp.x = pk2(hv.x, hv.y); hp.y = pk2(hv.z, hv.w);
      *(uint2*)(smem + bo) = xp;
      *(uint2*)(smem + 8192 + bo) = hp;
    }
  }
  __syncthreads();

  auto ldsA = [&](const ushort* base, int mr, int k0) -> bf16x8 {
    int row = mr * 16 + l15;
    int bo = (row * 256 + (k0 + q * 8) * 2) ^ ((row & 7) << 4);
    return *(const bf16x8*)((const char*)base + bo);
  };

  // ------- pass 1 (no rh needed): accr = x@Wr+h@Ur, accz = x@Wz+h@Uz, acch = x@Wh
  f32x4 accr[2], accz[2], acch[2];
#pragma unroll
  for (int mr = 0; mr < 2; ++mr) {
    accr[mr] = splat4(brv); accz[mr] = splat4(bzv); acch[mr] = splat4(bhv);
  }
#pragma unroll
  for (int kb = 0; kb < 4; ++kb) {
    bf16x8 bWz = *wfrag(0, kb);
    bf16x8 bUz = *wfrag(1, kb);
    bf16x8 bWr = *wfrag(2, kb);
    bf16x8 bUr = *wfrag(3, kb);
    bf16x8 bWh = *wfrag(4, kb);
#pragma unroll
    for (int mr = 0; mr < 2; ++mr) {
      bf16x8 ax = ldsA(xs, mr, kb * 32);
      bf16x8 ah = ldsA(hs, mr, kb * 32);
      accr[mr] = MFMA(ax, bWr, accr[mr], 0, 0, 0);
      accr[mr] = MFMA(ah, bUr, accr[mr], 0, 0, 0);
      accz[mr] = MFMA(ax, bWz, accz[mr], 0, 0, 0);
      accz[mr] = MFMA(ah, bUz, accz[mr], 0, 0, 0);
      acch[mr] = MFMA(ax, bWh, acch[mr], 0, 0, 0);
    }
  }

  // prefetch Uh fragments (cover L2 latency under the two barriers)
  bf16x8 bUh0 = *wfrag(5, 0), bUh1 = *wfrag(5, 1);
  bf16x8 bUh2 = *wfrag(5, 2), bUh3 = *wfrag(5, 3);

  __syncthreads();   // everyone done READING xs

  // rh = sigmoid(accr) * h_prev -> overwrite xs (cols n0..n0+15 per wave)
#pragma unroll
  for (int mr = 0; mr < 2; ++mr)
#pragma unroll
    for (int j = 0; j < 4; ++j) {
      int row = mr * 16 + q * 4 + j;
      int col = n0 + l15;
      float rv = fsig(accr[mr][j]);
      int bo = (row * 256 + col * 2) ^ ((row & 7) << 4);
      float hp = bf2f(*(const ushort*)((const char*)hs + bo));
      *(ushort*)((char*)xs + bo) = f2bf(rv * hp);
    }

  __syncthreads();   // all waves' rh visible

  // ------- pass 2: acch += rh @ Uh --------------------------------------
#pragma unroll
  for (int mr = 0; mr < 2; ++mr) {
    acch[mr] = MFMA(ldsA(xs, mr, 0),  bUh0, acch[mr], 0, 0, 0);
    acch[mr] = MFMA(ldsA(xs, mr, 32), bUh1, acch[mr], 0, 0, 0);
    acch[mr] = MFMA(ldsA(xs, mr, 64), bUh2, acch[mr], 0, 0, 0);
    acch[mr] = MFMA(ldsA(xs, mr, 96), bUh3, acch[mr], 0, 0, 0);
  }

  // ------- epilogue: h_t = hp + z*(hc - hp), into acch -------------------
#pragma unroll
  for (int mr = 0; mr < 2; ++mr)
#pragma unroll
    for (int j = 0; j < 4; ++j) {
      int row = mr * 16 + q * 4 + j;
      int col = n0 + l15;
      float hc = ftanh(acch[mr][j]);
      float zv = fsig(accz[mr][j]);
      int bo = (row * 256 + col * 2) ^ ((row & 7) << 4);
      float hp = bf2f(*(const ushort*)((const char*)hs + bo));
      acch[mr][j] = hp + zv * (hc - hp);
    }

  __syncthreads();   // done reading hs — reuse all 16 KB as f32 out-tile

  {
#pragma unroll
    for (int mr = 0; mr < 2; ++mr)
#pragma unroll
      for (int j = 0; j < 4; ++j) {
        int row = mr * 16 + q * 4 + j;
        int col = n0 + l15;
        int bo = (row * 512 + col * 4) ^ ((row & 7) << 4);
        *(float*)(smem + bo) = acch[mr][j];
      }
  }

  __syncthreads();

  // coalesced float4 stores
  {
#pragma unroll
    for (int i = 0; i < 2; ++i) {
      int idx = i * 512 + tid;        // float4 index 0..1023
      int row = idx >> 5;
      int c4 = idx & 31;
      int bo = (row * 512 + c4 * 16) ^ ((row & 7) << 4);
      float4 v = *(const float4*)(smem + bo);
      *(float4*)(out + (row0 + row) * 128 + c4 * 4) = v;
    }
  }
}

extern "C" void kernel_launch(void* const* d_in, const int* in_sizes, int n_in,
                              void* d_out, int out_size, void* d_ws, size_t ws_size,
                              hipStream_t stream) {
  const float* x  = (const float*)d_in[0];
  const float* h  = (const float*)d_in[1];
  const float* Wz = (const float*)d_in[2];
  const float* Uz = (const float*)d_in[3];
  const float* bz = (const float*)d_in[4];
  const float* Wr = (const float*)d_in[5];
  const float* Ur = (const float*)d_in[6];
  const float* br = (const float*)d_in[7];
  const float* Wh = (const float*)d_in[8];
  const float* Uh = (const float*)d_in[9];
  const float* bh = (const float*)d_in[10];
  ushort* wt = (ushort*)d_ws;   // 98304 bf16 = 192 KB packed fragment order

  hipLaunchKernelGGL(wtrans_kernel, dim3(384), dim3(256), 0, stream,
                     Wz, Uz, Wr, Ur, Wh, Uh, wt);
  hipLaunchKernelGGL(gru_kernel, dim3(GRU_B / BM), dim3(512), 0, stream,
                     x, h, wt, bz, br, bh, (float*)d_out);
}